// Round 13
// baseline (2248.423 us; speedup 1.0000x reference)
//
#include <hip/hip_runtime.h>

#define B_SZ 1024
#define T_SZ 128
#define HID 512
#define FEAT 128
#define LAB 100

// ---- d_ws layout (byte offsets, 16B-aligned) ----
#define OFF_X     0u          // int[262144]
#define OFF_WH    1048576u    // ushort[512*512]
#define OFF_LEN   1572864u    // ushort[96000]
#define OFF_IPD   1764864u    // ushort[16384]
#define OFF_FC2   1797632u    // ushort[51200]
#define OFF_WCH   1900032u    // ushort[65536]
#define OFF_WCL   2031104u    // ushort[65536]
#define OFF_BTOT  2162176u    // float[512]
#define OFF_FC2B  2164224u    // float[100] (+pad)
#define WS_NEED   2164736u

typedef __attribute__((ext_vector_type(8))) short short8;
typedef __attribute__((ext_vector_type(4))) float float4v;
typedef __attribute__((ext_vector_type(8))) __bf16 bf8_t;
typedef unsigned long long ull;

__device__ __attribute__((aligned(16))) unsigned char g_blob[WS_NEED]; // fallback only

__device__ __forceinline__ float bf2f(unsigned short u) {
    union { unsigned int i; float f; } z; z.i = ((unsigned int)u) << 16; return z.f;
}
__device__ __forceinline__ unsigned short f2bf(float f) {
    union { float f; unsigned int i; } z; z.f = f;
    unsigned int r = z.i + 0x7FFFu + ((z.i >> 16) & 1u);
    return (unsigned short)(r >> 16);
}
__device__ __forceinline__ float4v mfma16(short8 a, short8 b, float4v c) {
    return __builtin_amdgcn_mfma_f32_16x16x32_bf16(
        __builtin_bit_cast(bf8_t, a), __builtin_bit_cast(bf8_t, b), c, 0, 0, 0);
}
// h LDS layout, XOR-chunk swizzled (16B chunks) for bank uniformity
__device__ __forceinline__ int h_addr(int p, int m, int k) {
    return p * 8192 + m * 512 + ((((k >> 3)) ^ m) & 63) * 8 + (k & 7);
}

__global__ void conv_x_kernel(const int* __restrict__ xi, int* __restrict__ xo) {
    __shared__ int is64;
    if (threadIdx.x == 0) {
        int nz = 0;
        for (int j = 1; j < 64; j += 2) nz |= xi[j];
        is64 = (nz == 0) ? 1 : 0;
    }
    __syncthreads();
    const int n = B_SZ * T_SZ * 2;
    const int i64 = is64;
    for (int i = blockIdx.x * blockDim.x + threadIdx.x; i < n; i += gridDim.x * blockDim.x) {
        int v = i64 ? xi[2 * i] : xi[i];
        v = v < 0 ? 0 : (v > 255 ? 255 : v);
        xo[i] = v;
    }
}

__global__ void conv_floats_kernel(const float* __restrict__ len_e, const float* __restrict__ ipd_e,
                                   const float* __restrict__ h2h, const float* __restrict__ fc2,
                                   const float* __restrict__ fc2b,
                                   unsigned short* __restrict__ o_len, unsigned short* __restrict__ o_ipd,
                                   unsigned short* __restrict__ o_wh, unsigned short* __restrict__ o_fc2,
                                   float* __restrict__ o_fc2b) {
    const int N0 = 1500 * 64, N1 = 256 * 64, N2 = HID * HID, N3 = LAB * HID, N4 = LAB;
    const int total = N0 + N1 + N2 + N3 + N4;
    for (int i = blockIdx.x * blockDim.x + threadIdx.x; i < total; i += gridDim.x * blockDim.x) {
        int j = i;
        if (j < N0) { o_len[j] = f2bf(len_e[j]); continue; }
        j -= N0;
        if (j < N1) { o_ipd[j] = f2bf(ipd_e[j]); continue; }
        j -= N1;
        if (j < N2) { o_wh[j] = f2bf(h2h[j]); continue; }
        j -= N2;
        if (j < N3) { o_fc2[j] = f2bf(fc2[j]); continue; }
        j -= N3;
        o_fc2b[j] = fc2b[j];
    }
}

__global__ void prep_kernel(const float* __restrict__ fc1w, const float* __restrict__ fc1b,
                            const float* __restrict__ x2hw, const float* __restrict__ x2hb,
                            const float* __restrict__ h2hb,
                            unsigned short* __restrict__ o_wch, unsigned short* __restrict__ o_wcl,
                            float* __restrict__ o_btot) {
    int tid = threadIdx.x;
    int nl  = tid >> 5;
    int f0  = (tid & 31) << 2;
    int n   = blockIdx.x * 8 + nl;
    float a0 = 0.f, a1 = 0.f, a2 = 0.f, a3 = 0.f;
    for (int k = 0; k < 128; k++) {
        float a = x2hw[n * 128 + k];
        const float* fr = fc1w + k * 128 + f0;
        a0 += a * fr[0]; a1 += a * fr[1]; a2 += a * fr[2]; a3 += a * fr[3];
    }
    float vs[4] = {a0, a1, a2, a3};
    for (int j = 0; j < 4; j++) {
        unsigned short h = f2bf(vs[j]);
        o_wch[n * 128 + f0 + j] = h;
        o_wcl[n * 128 + f0 + j] = f2bf(vs[j] - bf2f(h));
    }
    if ((tid & 31) == 0) {
        float s = 0.f;
        for (int k = 0; k < 128; k++) s += x2hw[n * 128 + k] * fc1b[k];
        o_btot[n] = s + x2hb[n] + h2hb[n];
    }
}

// ---------------------------------------------------------------------------
// Self-contained RNN: 64 blocks x 512 threads, one block = 16 batch rows,
// FULL hidden state. Wh lives entirely in VGPRs (8 waves x 64 rows x 512 k
// bf16 = 256 VGPRs/wave); Wc hi/lo in VGPRs (128/wave); h (16x512 hi/lo,
// 32 KB) in LDS. Zero cross-block communication: 2 plain barriers/step.
//   A-frag = W rows : A[row=lane&15 -> hidden n][k=q*8+j]
//   B-frag = h^T    : B[col=lane&15 -> batch m][k=q*8+j]
//   C/D    : row=q*4+r -> hidden n, col=lane&15 -> batch m
// ---------------------------------------------------------------------------
__launch_bounds__(512, 1)
__global__ void rnn_kernel(const int* __restrict__ w_x,
                           const unsigned short* __restrict__ w_len,
                           const unsigned short* __restrict__ w_ipd,
                           const unsigned short* __restrict__ w_wh,
                           const unsigned short* __restrict__ w_fc2,
                           const float* __restrict__ w_fc2b,
                           const unsigned short* __restrict__ w_wch,
                           const unsigned short* __restrict__ w_wcl,
                           const float* __restrict__ w_btot,
                           float* __restrict__ out) {
    __shared__ __attribute__((aligned(16))) unsigned short sH[2 * 16 * 512]; // 32 KB

    const int tid  = threadIdx.x;
    const int wv   = tid >> 6;             // 0..7, owns hidden rows wv*64..wv*64+63
    const int ln   = tid & 63;
    const int mcol = ln & 15;
    const int q    = ln >> 4;
    const int g    = blockIdx.x;
    const int b0   = g * 16;
    const int n0   = wv * 64;

    // ---- Wh A-frags into registers: [n-tile][kt], 256 VGPRs ----
    short8 wh[4][16];
#pragma unroll
    for (int nt = 0; nt < 4; nt++)
#pragma unroll
        for (int kt = 0; kt < 16; kt++)
            wh[nt][kt] = *(const short8*)(w_wh + (n0 + nt * 16 + mcol) * 512 + kt * 32 + q * 8);

    // ---- Wc hi/lo frags: [n-tile][kt], 128 VGPRs ----
    short8 wc_hi[4][4], wc_lo[4][4];
#pragma unroll
    for (int nt = 0; nt < 4; nt++)
#pragma unroll
        for (int kt = 0; kt < 4; kt++) {
            int off = (n0 + nt * 16 + mcol) * 128 + kt * 32 + q * 8;
            wc_hi[nt][kt] = *(const short8*)(w_wch + off);
            wc_lo[nt][kt] = *(const short8*)(w_wcl + off);
        }
    float4v bt[4];
#pragma unroll
    for (int nt = 0; nt < 4; nt++)
        bt[nt] = *(const float4v*)(w_btot + n0 + nt * 16 + q * 4);

    // ---- zero h ----
    for (int i = 0; i < 4; i++) {
        uint4 z = {0, 0, 0, 0};
        *(uint4*)&sH[(i * 512 + tid) * 8] = z;
    }
    __syncthreads();

    for (int t = 0; t < T_SZ; t++) {
        // ---- feats B-frags straight to registers ----
        short8 ff[4];
        {
            int xoff = (b0 + mcol) * 256 + t * 2;
            int i0 = w_x[xoff], i1 = w_x[xoff + 1];
            const unsigned short* lr = w_len + i0 * 64 + q * 8;
            const unsigned short* ir = w_ipd + i1 * 64 + q * 8;
            ff[0] = *(const short8*)lr;  ff[1] = *(const short8*)(lr + 32);
            ff[2] = *(const short8*)ir;  ff[3] = *(const short8*)(ir + 32);
        }
        // ---- h-independent Wc MFMAs ----
        float4v acc[4];
#pragma unroll
        for (int nt = 0; nt < 4; nt++) acc[nt] = bt[nt];
#pragma unroll
        for (int kt = 0; kt < 4; kt++)
#pragma unroll
            for (int nt = 0; nt < 4; nt++) {
                acc[nt] = mfma16(wc_hi[nt][kt], ff[kt], acc[nt]);
                acc[nt] = mfma16(wc_lo[nt][kt], ff[kt], acc[nt]);
            }
        __syncthreads();   // (A) h_t writes from step t-1 visible

        // ---- Wh MFMAs: W from regs, h hi/lo from LDS ----
#pragma unroll 4
        for (int kt = 0; kt < 16; kt++) {
            int k = kt * 32 + q * 8;
            short8 bhi = *(const short8*)&sH[h_addr(0, mcol, k)];
            short8 blo = *(const short8*)&sH[h_addr(1, mcol, k)];
#pragma unroll
            for (int nt = 0; nt < 4; nt++) {
                acc[nt] = mfma16(wh[nt][kt], bhi, acc[nt]);
                acc[nt] = mfma16(wh[nt][kt], blo, acc[nt]);
            }
        }
        __syncthreads();   // (B) all sH reads of step t done

        // ---- tanh -> hi/lo; overwrite sH in place ----
#pragma unroll
        for (int nt = 0; nt < 4; nt++) {
            unsigned short hi4[4], lo4[4];
#pragma unroll
            for (int r = 0; r < 4; r++) {
                float v = fminf(15.f, fmaxf(-15.f, acc[nt][r]));
                float e = __expf(2.0f * v);
                float th = 1.0f - 2.0f / (e + 1.0f);
                hi4[r] = f2bf(th);
                lo4[r] = f2bf(th - bf2f(hi4[r]));
            }
            int nl = n0 + nt * 16 + q * 4;
            union { ull u8; uint2 v2; } vh, vl;
            vh.u8 = (ull)hi4[0] | ((ull)hi4[1] << 16) | ((ull)hi4[2] << 32) | ((ull)hi4[3] << 48);
            vl.u8 = (ull)lo4[0] | ((ull)lo4[1] << 16) | ((ull)lo4[2] << 32) | ((ull)lo4[3] << 48);
            *(uint2*)&sH[h_addr(0, mcol, nl)] = vh.v2;
            *(uint2*)&sH[h_addr(1, mcol, nl)] = vl.v2;
        }
        // next iteration's barrier (A) orders these writes before the reads
    }
    __syncthreads();

    // ---- fc2 epilogue: out^T = fc2 * h_last^T (waves 0..6 cover 112 >= 100) ----
    if (wv < 7) {
        int lA = wv * 16 + mcol; if (lA > 99) lA = 99;
        float4v a2 = {0.f, 0.f, 0.f, 0.f};
#pragma unroll 4
        for (int kt = 0; kt < 16; kt++) {
            int k = kt * 32 + q * 8;
            short8 fa  = *(const short8*)(w_fc2 + lA * 512 + k);
            short8 bhi = *(const short8*)&sH[h_addr(0, mcol, k)];
            short8 blo = *(const short8*)&sH[h_addr(1, mcol, k)];
            a2 = mfma16(fa, bhi, a2);
            a2 = mfma16(fa, blo, a2);
        }
#pragma unroll
        for (int r = 0; r < 4; r++) {
            int l = wv * 16 + q * 4 + r;
            if (l < 100) out[(b0 + mcol) * 100 + l] = a2[r] + w_fc2b[l];
        }
    }
}

extern "C" void kernel_launch(void* const* d_in, const int* in_sizes, int n_in,
                              void* d_out, int out_size, void* d_ws, size_t ws_size,
                              hipStream_t stream) {
    unsigned char* base = (unsigned char*)d_ws;
    if (ws_size < (size_t)WS_NEED) {
        void* p = nullptr;
        hipGetSymbolAddress(&p, HIP_SYMBOL(g_blob));
        base = (unsigned char*)p;
    }
    int*            w_x    = (int*)(base + OFF_X);
    unsigned short* w_wh   = (unsigned short*)(base + OFF_WH);
    unsigned short* w_len  = (unsigned short*)(base + OFF_LEN);
    unsigned short* w_ipd  = (unsigned short*)(base + OFF_IPD);
    unsigned short* w_fc2  = (unsigned short*)(base + OFF_FC2);
    unsigned short* w_wch  = (unsigned short*)(base + OFF_WCH);
    unsigned short* w_wcl  = (unsigned short*)(base + OFF_WCL);
    float*          w_btot = (float*)(base + OFF_BTOT);
    float*          w_fc2b = (float*)(base + OFF_FC2B);

    conv_x_kernel<<<256, 256, 0, stream>>>((const int*)d_in[0], w_x);
    conv_floats_kernel<<<1024, 256, 0, stream>>>(
        (const float*)d_in[1], (const float*)d_in[2], (const float*)d_in[7],
        (const float*)d_in[9], (const float*)d_in[10],
        w_len, w_ipd, w_wh, w_fc2, w_fc2b);
    prep_kernel<<<64, 256, 0, stream>>>(
        (const float*)d_in[3], (const float*)d_in[4], (const float*)d_in[5],
        (const float*)d_in[6], (const float*)d_in[8],
        w_wch, w_wcl, w_btot);
    rnn_kernel<<<64, 512, 0, stream>>>(
        w_x, w_len, w_ipd, w_wh, w_fc2, w_fc2b, w_wch, w_wcl, w_btot,
        (float*)d_out);
}

// Round 14
// 660.556 us; speedup vs baseline: 3.4038x; 3.4038x over previous
//
#include <hip/hip_runtime.h>

#define B_SZ 1024
#define T_SZ 128
#define HID 512
#define LAB 100

// ---- d_ws layout (byte offsets) ----
#define OFF_X     0u          // int[262144]          1 MB
#define OFF_WH    1048576u    // ushort[262144]       512 KB
#define OFF_LEN   1572864u    // ushort[96000]
#define OFF_IPD   1764864u    // ushort[16384]
#define OFF_FC2   1797632u    // ushort[51200]
#define OFF_X2H   1900032u    // ushort[65536]        128 KB
#define OFF_FC2B  2031104u    // float[100] (+pad)
#define OFF_XIN   2097152u    // ushort[128][64][16][512] = 128 MB
#define WS_NEED   136314880u

typedef __attribute__((ext_vector_type(8))) short short8;
typedef __attribute__((ext_vector_type(4))) float float4v;
typedef __attribute__((ext_vector_type(4))) unsigned short us4;
typedef __attribute__((ext_vector_type(8))) __bf16 bf8_t;
typedef unsigned long long ull;

__device__ __attribute__((aligned(16))) unsigned char g_blob[WS_NEED]; // fallback only

__device__ __forceinline__ float bf2f(unsigned short u) {
    union { unsigned int i; float f; } z; z.i = ((unsigned int)u) << 16; return z.f;
}
__device__ __forceinline__ unsigned short f2bf(float f) {
    union { float f; unsigned int i; } z; z.f = f;
    unsigned int r = z.i + 0x7FFFu + ((z.i >> 16) & 1u);
    return (unsigned short)(r >> 16);
}
__device__ __forceinline__ float4v mfma16(short8 a, short8 b, float4v c) {
    return __builtin_amdgcn_mfma_f32_16x16x32_bf16(
        __builtin_bit_cast(bf8_t, a), __builtin_bit_cast(bf8_t, b), c, 0, 0, 0);
}
// h LDS: [m][k] 16x512 ushort, XOR-chunk swizzle (proven R12 pattern)
__device__ __forceinline__ int h_addr(int m, int k) {
    return m * 512 + ((((k >> 3)) ^ m) & 63) * 8 + (k & 7);
}

__global__ void conv_x_kernel(const int* __restrict__ xi, int* __restrict__ xo) {
    __shared__ int is64;
    if (threadIdx.x == 0) {
        int nz = 0;
        for (int j = 1; j < 64; j += 2) nz |= xi[j];
        is64 = (nz == 0) ? 1 : 0;
    }
    __syncthreads();
    const int n = B_SZ * T_SZ * 2;
    const int i64 = is64;
    for (int i = blockIdx.x * blockDim.x + threadIdx.x; i < n; i += gridDim.x * blockDim.x) {
        int v = i64 ? xi[2 * i] : xi[i];
        v = v < 0 ? 0 : (v > 255 ? 255 : v);
        xo[i] = v;
    }
}

__global__ void conv_floats_kernel(const float* __restrict__ len_e, const float* __restrict__ ipd_e,
                                   const float* __restrict__ h2h, const float* __restrict__ fc2,
                                   const float* __restrict__ x2h, const float* __restrict__ fc2b,
                                   unsigned short* __restrict__ o_len, unsigned short* __restrict__ o_ipd,
                                   unsigned short* __restrict__ o_wh, unsigned short* __restrict__ o_fc2,
                                   unsigned short* __restrict__ o_x2h, float* __restrict__ o_fc2b) {
    const int N0 = 96000, N1 = 16384, N2 = 262144, N3 = 51200, N4 = 65536, N5 = 100;
    const int total = N0 + N1 + N2 + N3 + N4 + N5;
    for (int i = blockIdx.x * blockDim.x + threadIdx.x; i < total; i += gridDim.x * blockDim.x) {
        int j = i;
        if (j < N0) { o_len[j] = f2bf(len_e[j]); continue; }
        j -= N0;
        if (j < N1) { o_ipd[j] = f2bf(ipd_e[j]); continue; }
        j -= N1;
        if (j < N2) { o_wh[j] = f2bf(h2h[j]); continue; }
        j -= N2;
        if (j < N3) { o_fc2[j] = f2bf(fc2[j]); continue; }
        j -= N3;
        if (j < N4) { o_x2h[j] = f2bf(x2h[j]); continue; }
        j -= N4;
        o_fc2b[j] = fc2b[j];
    }
}

// ---------------------------------------------------------------------------
// xin_kernel: xin[t][g][m][n] = (feats @ fc1^T + fc1_b) @ x2h^T + x2h_b + h2h_b
// 1024 blocks (t 0..127 x 8 b-groups of 128 rows) x 256 threads.
// LDS: fT (feats 128x136), fc1L (128x136), rT (r 128x136) = 102 KB dynamic.
// ---------------------------------------------------------------------------
__launch_bounds__(256)
__global__ void xin_kernel(const int* __restrict__ w_x,
                           const unsigned short* __restrict__ w_len,
                           const unsigned short* __restrict__ w_ipd,
                           const float* __restrict__ fc1w, const float* __restrict__ fc1b,
                           const unsigned short* __restrict__ w_x2h,
                           const float* __restrict__ x2hb, const float* __restrict__ h2hb,
                           unsigned short* __restrict__ w_xin) {
    extern __shared__ unsigned short sm[];
    unsigned short* fT   = sm;                // 128*136
    unsigned short* fc1L = sm + 128 * 136;    // 128*136
    unsigned short* rT   = sm + 2 * 128 * 136;

    const int tid  = threadIdx.x;
    const int wv   = tid >> 6;
    const int ln   = tid & 63;
    const int mcol = ln & 15;
    const int q    = ln >> 4;
    const int t    = blockIdx.x >> 3;
    const int bg   = blockIdx.x & 7;

    // ---- gather feats tile (128 rows x 128 feats bf16) ----
    {
        int row = tid >> 1, c = tid & 1;
        int idx = w_x[(bg * 128 + row) * 256 + t * 2 + c];
        const uint4* s4 = (const uint4*)((c ? w_ipd : w_len) + idx * 64);
        uint4* dst = (uint4*)&fT[row * 136 + c * 64];
#pragma unroll
        for (int i = 0; i < 8; i++) dst[i] = s4[i];
    }
    // ---- stage fc1 (f32 -> bf16) ----
#pragma unroll
    for (int it = 0; it < 8; it++) {
        int chunk = it * 256 + tid;          // 0..2047
        int r = chunk >> 4, c8 = chunk & 15;
        const float* s = fc1w + r * 128 + c8 * 8;
        us4 a = { f2bf(s[0]), f2bf(s[1]), f2bf(s[2]), f2bf(s[3]) };
        us4 b = { f2bf(s[4]), f2bf(s[5]), f2bf(s[6]), f2bf(s[7]) };
        *(us4*)&fc1L[r * 136 + c8 * 8]     = a;
        *(us4*)&fc1L[r * 136 + c8 * 8 + 4] = b;
    }
    __syncthreads();

    // ---- r-stage: wave w owns n'-tiles {w, w+4} ----
    for (int mt = 0; mt < 8; mt++) {
        float4v acc[2] = {{0.f,0.f,0.f,0.f},{0.f,0.f,0.f,0.f}};
#pragma unroll
        for (int kt = 0; kt < 4; kt++) {
            short8 bf = *(const short8*)&fT[(mt * 16 + mcol) * 136 + kt * 32 + q * 8];
#pragma unroll
            for (int u = 0; u < 2; u++) {
                int ntp = wv + u * 4;
                short8 fa = *(const short8*)&fc1L[(ntp * 16 + mcol) * 136 + kt * 32 + q * 8];
                acc[u] = mfma16(fa, bf, acc[u]);
            }
        }
#pragma unroll
        for (int u = 0; u < 2; u++) {
            int ntp = wv + u * 4;
            unsigned short o[4];
#pragma unroll
            for (int r = 0; r < 4; r++)
                o[r] = f2bf(acc[u][r] + fc1b[ntp * 16 + q * 4 + r]);
            us4 v = { o[0], o[1], o[2], o[3] };
            *(us4*)&rT[(mt * 16 + mcol) * 136 + ntp * 16 + q * 4] = v;
        }
    }
    __syncthreads();

    // ---- xin-stage: wave w owns n-tiles w*8..w*8+7 ----
    float bias[8][4];
#pragma unroll
    for (int i = 0; i < 8; i++)
#pragma unroll
        for (int r = 0; r < 4; r++) {
            int n = (wv * 8 + i) * 16 + q * 4 + r;
            bias[i][r] = x2hb[n] + h2hb[n];
        }
    for (int mt = 0; mt < 8; mt++) {
        float4v acc[8];
#pragma unroll
        for (int i = 0; i < 8; i++) acc[i] = (float4v){0.f,0.f,0.f,0.f};
#pragma unroll
        for (int kt = 0; kt < 4; kt++) {
            short8 bf = *(const short8*)&rT[(mt * 16 + mcol) * 136 + kt * 32 + q * 8];
#pragma unroll
            for (int i = 0; i < 8; i++) {
                int n16 = (wv * 8 + i) * 16;
                short8 fa = *(const short8*)(w_x2h + (n16 + mcol) * 128 + kt * 32 + q * 8);
                acc[i] = mfma16(fa, bf, acc[i]);
            }
        }
        int m = mt * 16 + mcol;
        int g = bg * 8 + (m >> 4), mm = m & 15;
#pragma unroll
        for (int i = 0; i < 8; i++) {
            int n0i = (wv * 8 + i) * 16 + q * 4;
            us4 v = { f2bf(acc[i][0] + bias[i][0]), f2bf(acc[i][1] + bias[i][1]),
                      f2bf(acc[i][2] + bias[i][2]), f2bf(acc[i][3] + bias[i][3]) };
            *(us4*)&w_xin[((t * 64 + g) * 16 + mm) * 512 + n0i] = v;
        }
    }
}

// ---------------------------------------------------------------------------
// RNN: 64 blocks x 256 threads (4 waves = 1/SIMD -> 512-VGPR budget).
// Wh: kt 0..11 in 384 VGPRs/thread; kt 12..15 in 128 KB LDS. h single-plane
// bf16 in 16 KB LDS. xin streamed with 1-step register prefetch. No Wc, no
// cross-block sync. Per wave: 8 n-tiles (128 hidden rows).
// ---------------------------------------------------------------------------
__launch_bounds__(256, 1)
__global__ void rnn_kernel(const unsigned short* __restrict__ w_wh,
                           const unsigned short* __restrict__ w_xin,
                           const unsigned short* __restrict__ w_fc2,
                           const float* __restrict__ w_fc2b,
                           float* __restrict__ out) {
    extern __shared__ unsigned short sm2[];
    unsigned short* sA = sm2;            // Wh k 384..511: [r][k'] swizzled, 65536 ushorts
    unsigned short* sH = sm2 + 65536;    // h: 16x512 swizzled, 8192 ushorts

    const int tid  = threadIdx.x;
    const int wv   = tid >> 6;           // 0..3
    const int ln   = tid & 63;
    const int mcol = ln & 15;
    const int q    = ln >> 4;
    const int g    = blockIdx.x;
    const int b0   = g * 16;
    const int n0   = wv * 128;

    // ---- stage Wh kt 12..15 into LDS (swizzled) ----
    for (int it = 0; it < 32; it++) {
        int chunk = it * 256 + tid;          // 0..8191
        int r = chunk >> 4, c = chunk & 15;
        uint4 v = *(const uint4*)(w_wh + r * 512 + 384 + c * 8);
        *(uint4*)&sA[r * 128 + ((c ^ (r & 15)) & 15) * 8] = v;
    }
    // ---- zero h ----
    for (int it = 0; it < 4; it++) {
        uint4 z = {0, 0, 0, 0};
        *(uint4*)&sH[(it * 256 + tid) * 8] = z;
    }
    // ---- Wh kt 0..11 into registers: 96 frags = 384 VGPRs ----
    short8 whr[8][12];
#pragma unroll
    for (int nt = 0; nt < 8; nt++)
#pragma unroll
        for (int kt = 0; kt < 12; kt++)
            whr[nt][kt] = *(const short8*)(w_wh + (n0 + nt * 16 + mcol) * 512 + kt * 32 + q * 8);

    // ---- xin prefetch (t=0) ----
    const unsigned short* xin_b = w_xin + (g * 16 + mcol) * 512 + n0 + q * 4;
    us4 xq[8];
#pragma unroll
    for (int nt = 0; nt < 8; nt++)
        xq[nt] = *(const us4*)(xin_b + nt * 16);

    __syncthreads();

    for (int t = 0; t < T_SZ; t++) {
        // ---- acc init from prefetched xin ----
        float4v acc[8];
#pragma unroll
        for (int nt = 0; nt < 8; nt++) {
            acc[nt][0] = bf2f(xq[nt][0]); acc[nt][1] = bf2f(xq[nt][1]);
            acc[nt][2] = bf2f(xq[nt][2]); acc[nt][3] = bf2f(xq[nt][3]);
        }
        // ---- prefetch xin(t+1) ----
        if (t + 1 < T_SZ) {
            const unsigned short* xb = xin_b + (ull)(t + 1) * 64 * 16 * 512;
#pragma unroll
            for (int nt = 0; nt < 8; nt++)
                xq[nt] = *(const us4*)(xb + nt * 16);
        }
        __syncthreads();   // (A) h_t ready

        // ---- Wh MFMAs: kt 0..11 from regs ----
#pragma unroll
        for (int kt = 0; kt < 12; kt++) {
            short8 bh = *(const short8*)&sH[mcol * 512 + (((kt * 4 + q) ^ mcol) & 63) * 8];
#pragma unroll
            for (int nt = 0; nt < 8; nt++)
                acc[nt] = mfma16(whr[nt][kt], bh, acc[nt]);
        }
        // ---- kt 12..15 from LDS ----
#pragma unroll
        for (int kt = 12; kt < 16; kt++) {
            short8 bh = *(const short8*)&sH[mcol * 512 + (((kt * 4 + q) ^ mcol) & 63) * 8];
            int c = (kt - 12) * 4 + q;
#pragma unroll
            for (int nt = 0; nt < 8; nt++) {
                int r = n0 + nt * 16 + mcol;
                short8 fa = *(const short8*)&sA[r * 128 + ((c ^ mcol) & 15) * 8];
                acc[nt] = mfma16(fa, bh, acc[nt]);
            }
        }
        __syncthreads();   // (B) all h reads done

        // ---- tanh -> bf16, write h in place ----
#pragma unroll
        for (int nt = 0; nt < 8; nt++) {
            unsigned short o[4];
#pragma unroll
            for (int r = 0; r < 4; r++) {
                float v = fminf(15.f, fmaxf(-15.f, acc[nt][r]));
                float e = __expf(2.0f * v);
                o[r] = f2bf(1.0f - 2.0f / (e + 1.0f));
            }
            int n = n0 + nt * 16 + q * 4;
            us4 v4 = { o[0], o[1], o[2], o[3] };
            *(us4*)&sH[mcol * 512 + (((n >> 3) ^ mcol) & 63) * 8 + (n & 7)] = v4;
        }
    }
    __syncthreads();

    // ---- fc2 epilogue: l-tiles 0..6 over waves 0..3 ----
#pragma unroll
    for (int u = 0; u < 2; u++) {
        int lt = wv + u * 4;
        if (lt >= 7) break;
        int lA = lt * 16 + mcol; if (lA > 99) lA = 99;
        float4v a2 = {0.f, 0.f, 0.f, 0.f};
#pragma unroll 4
        for (int kt = 0; kt < 16; kt++) {
            short8 fa = *(const short8*)(w_fc2 + lA * 512 + kt * 32 + q * 8);
            short8 bh = *(const short8*)&sH[mcol * 512 + (((kt * 4 + q) ^ mcol) & 63) * 8];
            a2 = mfma16(fa, bh, a2);
        }
#pragma unroll
        for (int r = 0; r < 4; r++) {
            int l = lt * 16 + q * 4 + r;
            if (l < 100) out[(b0 + mcol) * 100 + l] = a2[r] + w_fc2b[l];
        }
    }
}

extern "C" void kernel_launch(void* const* d_in, const int* in_sizes, int n_in,
                              void* d_out, int out_size, void* d_ws, size_t ws_size,
                              hipStream_t stream) {
    unsigned char* base = (unsigned char*)d_ws;
    if (ws_size < (size_t)WS_NEED) {
        void* p = nullptr;
        hipGetSymbolAddress(&p, HIP_SYMBOL(g_blob));
        base = (unsigned char*)p;
    }
    int*            w_x    = (int*)(base + OFF_X);
    unsigned short* w_wh   = (unsigned short*)(base + OFF_WH);
    unsigned short* w_len  = (unsigned short*)(base + OFF_LEN);
    unsigned short* w_ipd  = (unsigned short*)(base + OFF_IPD);
    unsigned short* w_fc2  = (unsigned short*)(base + OFF_FC2);
    unsigned short* w_x2h  = (unsigned short*)(base + OFF_X2H);
    float*          w_fc2b = (float*)(base + OFF_FC2B);
    unsigned short* w_xin  = (unsigned short*)(base + OFF_XIN);

    static bool attr_set = false;
    if (!attr_set) {
        hipFuncSetAttribute((const void*)xin_kernel,
                            hipFuncAttributeMaxDynamicSharedMemorySize, 3 * 128 * 136 * 2);
        hipFuncSetAttribute((const void*)rnn_kernel,
                            hipFuncAttributeMaxDynamicSharedMemorySize, 147456);
        attr_set = true;
    }

    conv_x_kernel<<<256, 256, 0, stream>>>((const int*)d_in[0], w_x);
    conv_floats_kernel<<<1024, 256, 0, stream>>>(
        (const float*)d_in[1], (const float*)d_in[2], (const float*)d_in[7],
        (const float*)d_in[9], (const float*)d_in[5], (const float*)d_in[10],
        w_len, w_ipd, w_wh, w_fc2, w_x2h, w_fc2b);
    xin_kernel<<<1024, 256, 3 * 128 * 136 * 2, stream>>>(
        w_x, w_len, w_ipd,
        (const float*)d_in[3], (const float*)d_in[4],
        w_x2h, (const float*)d_in[6], (const float*)d_in[8],
        w_xin);
    rnn_kernel<<<64, 256, 147456, stream>>>(
        w_wh, w_xin, w_fc2, w_fc2b, (float*)d_out);
}

// Round 15
// 487.001 us; speedup vs baseline: 4.6169x; 1.3564x over previous
//
#include <hip/hip_runtime.h>

#define B_SZ 1024
#define T_SZ 128
#define HID 512
#define LAB 100

// ---- d_ws layout (byte offsets) ----
#define OFF_X     0u          // int[262144]          1 MB
#define OFF_WH    1048576u    // ushort[262144]       512 KB
#define OFF_LEN   1572864u    // ushort[96000]
#define OFF_IPD   1764864u    // ushort[16384]
#define OFF_FC2   1797632u    // ushort[51200]
#define OFF_X2H   1900032u    // ushort[65536]        128 KB
#define OFF_FC2B  2031104u    // float[100] (+pad)
#define OFF_XIN   2097152u    // ushort[128][64][16][512] = 128 MB
#define WS_NEED   136314880u

typedef __attribute__((ext_vector_type(8))) short short8;
typedef __attribute__((ext_vector_type(4))) float float4v;
typedef __attribute__((ext_vector_type(4))) unsigned short us4;
typedef __attribute__((ext_vector_type(8))) __bf16 bf8_t;
typedef unsigned long long ull;

__device__ __attribute__((aligned(16))) unsigned char g_blob[WS_NEED]; // fallback only

__device__ __forceinline__ float bf2f(unsigned short u) {
    union { unsigned int i; float f; } z; z.i = ((unsigned int)u) << 16; return z.f;
}
__device__ __forceinline__ unsigned short f2bf(float f) {
    union { float f; unsigned int i; } z; z.f = f;
    unsigned int r = z.i + 0x7FFFu + ((z.i >> 16) & 1u);
    return (unsigned short)(r >> 16);
}
__device__ __forceinline__ float4v mfma16(short8 a, short8 b, float4v c) {
    return __builtin_amdgcn_mfma_f32_16x16x32_bf16(
        __builtin_bit_cast(bf8_t, a), __builtin_bit_cast(bf8_t, b), c, 0, 0, 0);
}

__global__ void conv_x_kernel(const int* __restrict__ xi, int* __restrict__ xo) {
    __shared__ int is64;
    if (threadIdx.x == 0) {
        int nz = 0;
        for (int j = 1; j < 64; j += 2) nz |= xi[j];
        is64 = (nz == 0) ? 1 : 0;
    }
    __syncthreads();
    const int n = B_SZ * T_SZ * 2;
    const int i64 = is64;
    for (int i = blockIdx.x * blockDim.x + threadIdx.x; i < n; i += gridDim.x * blockDim.x) {
        int v = i64 ? xi[2 * i] : xi[i];
        v = v < 0 ? 0 : (v > 255 ? 255 : v);
        xo[i] = v;
    }
}

__global__ void conv_floats_kernel(const float* __restrict__ len_e, const float* __restrict__ ipd_e,
                                   const float* __restrict__ h2h, const float* __restrict__ fc2,
                                   const float* __restrict__ x2h, const float* __restrict__ fc2b,
                                   unsigned short* __restrict__ o_len, unsigned short* __restrict__ o_ipd,
                                   unsigned short* __restrict__ o_wh, unsigned short* __restrict__ o_fc2,
                                   unsigned short* __restrict__ o_x2h, float* __restrict__ o_fc2b) {
    const int N0 = 96000, N1 = 16384, N2 = 262144, N3 = 51200, N4 = 65536, N5 = 100;
    const int total = N0 + N1 + N2 + N3 + N4 + N5;
    for (int i = blockIdx.x * blockDim.x + threadIdx.x; i < total; i += gridDim.x * blockDim.x) {
        int j = i;
        if (j < N0) { o_len[j] = f2bf(len_e[j]); continue; }
        j -= N0;
        if (j < N1) { o_ipd[j] = f2bf(ipd_e[j]); continue; }
        j -= N1;
        if (j < N2) { o_wh[j] = f2bf(h2h[j]); continue; }
        j -= N2;
        if (j < N3) { o_fc2[j] = f2bf(fc2[j]); continue; }
        j -= N3;
        if (j < N4) { o_x2h[j] = f2bf(x2h[j]); continue; }
        j -= N4;
        o_fc2b[j] = fc2b[j];
    }
}

// ---------------------------------------------------------------------------
// xin_kernel: xin[t][g][m][n] = (feats @ fc1^T + fc1_b) @ x2h^T + x2h_b + h2h_b
// 1024 blocks (t x 8 b-groups of 128 rows) x 256 threads. (unchanged, proven)
// ---------------------------------------------------------------------------
__launch_bounds__(256)
__global__ void xin_kernel(const int* __restrict__ w_x,
                           const unsigned short* __restrict__ w_len,
                           const unsigned short* __restrict__ w_ipd,
                           const float* __restrict__ fc1w, const float* __restrict__ fc1b,
                           const unsigned short* __restrict__ w_x2h,
                           const float* __restrict__ x2hb, const float* __restrict__ h2hb,
                           unsigned short* __restrict__ w_xin) {
    extern __shared__ unsigned short sm[];
    unsigned short* fT   = sm;
    unsigned short* fc1L = sm + 128 * 136;
    unsigned short* rT   = sm + 2 * 128 * 136;

    const int tid  = threadIdx.x;
    const int wv   = tid >> 6;
    const int ln   = tid & 63;
    const int mcol = ln & 15;
    const int q    = ln >> 4;
    const int t    = blockIdx.x >> 3;
    const int bg   = blockIdx.x & 7;

    {
        int row = tid >> 1, c = tid & 1;
        int idx = w_x[(bg * 128 + row) * 256 + t * 2 + c];
        const uint4* s4 = (const uint4*)((c ? w_ipd : w_len) + idx * 64);
        uint4* dst = (uint4*)&fT[row * 136 + c * 64];
#pragma unroll
        for (int i = 0; i < 8; i++) dst[i] = s4[i];
    }
#pragma unroll
    for (int it = 0; it < 8; it++) {
        int chunk = it * 256 + tid;
        int r = chunk >> 4, c8 = chunk & 15;
        const float* s = fc1w + r * 128 + c8 * 8;
        us4 a = { f2bf(s[0]), f2bf(s[1]), f2bf(s[2]), f2bf(s[3]) };
        us4 b = { f2bf(s[4]), f2bf(s[5]), f2bf(s[6]), f2bf(s[7]) };
        *(us4*)&fc1L[r * 136 + c8 * 8]     = a;
        *(us4*)&fc1L[r * 136 + c8 * 8 + 4] = b;
    }
    __syncthreads();

    for (int mt = 0; mt < 8; mt++) {
        float4v acc[2] = {{0.f,0.f,0.f,0.f},{0.f,0.f,0.f,0.f}};
#pragma unroll
        for (int kt = 0; kt < 4; kt++) {
            short8 bf = *(const short8*)&fT[(mt * 16 + mcol) * 136 + kt * 32 + q * 8];
#pragma unroll
            for (int u = 0; u < 2; u++) {
                int ntp = wv + u * 4;
                short8 fa = *(const short8*)&fc1L[(ntp * 16 + mcol) * 136 + kt * 32 + q * 8];
                acc[u] = mfma16(fa, bf, acc[u]);
            }
        }
#pragma unroll
        for (int u = 0; u < 2; u++) {
            int ntp = wv + u * 4;
            unsigned short o[4];
#pragma unroll
            for (int r = 0; r < 4; r++)
                o[r] = f2bf(acc[u][r] + fc1b[ntp * 16 + q * 4 + r]);
            us4 v = { o[0], o[1], o[2], o[3] };
            *(us4*)&rT[(mt * 16 + mcol) * 136 + ntp * 16 + q * 4] = v;
        }
    }
    __syncthreads();

    float bias[8][4];
#pragma unroll
    for (int i = 0; i < 8; i++)
#pragma unroll
        for (int r = 0; r < 4; r++) {
            int n = (wv * 8 + i) * 16 + q * 4 + r;
            bias[i][r] = x2hb[n] + h2hb[n];
        }
    for (int mt = 0; mt < 8; mt++) {
        float4v acc[8];
#pragma unroll
        for (int i = 0; i < 8; i++) acc[i] = (float4v){0.f,0.f,0.f,0.f};
#pragma unroll
        for (int kt = 0; kt < 4; kt++) {
            short8 bf = *(const short8*)&rT[(mt * 16 + mcol) * 136 + kt * 32 + q * 8];
#pragma unroll
            for (int i = 0; i < 8; i++) {
                int n16 = (wv * 8 + i) * 16;
                short8 fa = *(const short8*)(w_x2h + (n16 + mcol) * 128 + kt * 32 + q * 8);
                acc[i] = mfma16(fa, bf, acc[i]);
            }
        }
        int m = mt * 16 + mcol;
        int g = bg * 8 + (m >> 4), mm = m & 15;
#pragma unroll
        for (int i = 0; i < 8; i++) {
            int n0i = (wv * 8 + i) * 16 + q * 4;
            us4 v = { f2bf(acc[i][0] + bias[i][0]), f2bf(acc[i][1] + bias[i][1]),
                      f2bf(acc[i][2] + bias[i][2]), f2bf(acc[i][3] + bias[i][3]) };
            *(us4*)&w_xin[((t * 64 + g) * 16 + mm) * 512 + n0i] = v;
        }
    }
}

// ---------------------------------------------------------------------------
// RNN: 64 blocks x 512 threads (8 waves, 2/SIMD -> latency hiding).
// Wave owns 64 hidden rows: Wh kt0..11 in 192 VGPRs; kt12..15 in 128 KB LDS.
// h DOUBLE-buffered bf16 (2x16 KB) -> ONE barrier per step. xin 1-step
// register prefetch. LDS total = 160 KB. No cross-block sync.
// ---------------------------------------------------------------------------
__launch_bounds__(512, 2)
__global__ void rnn_kernel(const unsigned short* __restrict__ w_wh,
                           const unsigned short* __restrict__ w_xin,
                           const unsigned short* __restrict__ w_fc2,
                           const float* __restrict__ w_fc2b,
                           float* __restrict__ out) {
    extern __shared__ unsigned short sm2[];
    unsigned short* sA = sm2;            // Wh k 384..511: 65536 ushorts (128 KB)
    unsigned short* sH = sm2 + 65536;    // h dbuf: 2 x 8192 ushorts (32 KB)

    const int tid  = threadIdx.x;
    const int wv   = tid >> 6;           // 0..7
    const int ln   = tid & 63;
    const int mcol = ln & 15;
    const int q    = ln >> 4;
    const int g    = blockIdx.x;
    const int b0   = g * 16;
    const int n0   = wv * 64;            // wave owns hidden rows n0..n0+63

    // ---- stage Wh kt 12..15 into LDS (swizzled) ----
    for (int it = 0; it < 16; it++) {
        int chunk = it * 512 + tid;          // 0..8191
        int r = chunk >> 4, c = chunk & 15;
        uint4 v = *(const uint4*)(w_wh + r * 512 + 384 + c * 8);
        *(uint4*)&sA[r * 128 + ((c ^ (r & 15)) & 15) * 8] = v;
    }
    // ---- zero h buffer 0 ----
    for (int it = 0; it < 2; it++) {
        uint4 z = {0, 0, 0, 0};
        *(uint4*)&sH[(it * 512 + tid) * 8] = z;
    }
    // ---- Wh kt 0..11 into registers: 48 frags = 192 VGPRs ----
    short8 whr[4][12];
#pragma unroll
    for (int nt = 0; nt < 4; nt++)
#pragma unroll
        for (int kt = 0; kt < 12; kt++)
            whr[nt][kt] = *(const short8*)(w_wh + (n0 + nt * 16 + mcol) * 512 + kt * 32 + q * 8);

    // ---- xin prefetch (t=0) ----
    const unsigned short* xin_b = w_xin + (g * 16 + mcol) * 512 + n0 + q * 4;
    us4 xq[4];
#pragma unroll
    for (int nt = 0; nt < 4; nt++)
        xq[nt] = *(const us4*)(xin_b + nt * 16);

    __syncthreads();

    for (int t = 0; t < T_SZ; t++) {
        const int p = t & 1;
        unsigned short* hRd = sH + p * 8192;
        unsigned short* hWr = sH + (1 - p) * 8192;

        // ---- acc init from prefetched xin ----
        float4v acc[4];
#pragma unroll
        for (int nt = 0; nt < 4; nt++) {
            acc[nt][0] = bf2f(xq[nt][0]); acc[nt][1] = bf2f(xq[nt][1]);
            acc[nt][2] = bf2f(xq[nt][2]); acc[nt][3] = bf2f(xq[nt][3]);
        }
        // ---- prefetch xin(t+1) ----
        if (t + 1 < T_SZ) {
            const unsigned short* xb = xin_b + (ull)(t + 1) * 64 * 16 * 512;
#pragma unroll
            for (int nt = 0; nt < 4; nt++)
                xq[nt] = *(const us4*)(xb + nt * 16);
        }

        // ---- Wh MFMAs: kt 0..11 from regs ----
#pragma unroll
        for (int kt = 0; kt < 12; kt++) {
            short8 bh = *(const short8*)&hRd[mcol * 512 + (((kt * 4 + q) ^ mcol) & 63) * 8];
#pragma unroll
            for (int nt = 0; nt < 4; nt++)
                acc[nt] = mfma16(whr[nt][kt], bh, acc[nt]);
        }
        // ---- kt 12..15 from LDS ----
#pragma unroll
        for (int kt = 12; kt < 16; kt++) {
            short8 bh = *(const short8*)&hRd[mcol * 512 + (((kt * 4 + q) ^ mcol) & 63) * 8];
            int c = (kt - 12) * 4 + q;
#pragma unroll
            for (int nt = 0; nt < 4; nt++) {
                int r = n0 + nt * 16 + mcol;
                short8 fa = *(const short8*)&sA[r * 128 + ((c ^ mcol) & 15) * 8];
                acc[nt] = mfma16(fa, bh, acc[nt]);
            }
        }

        // ---- tanh -> bf16, write h(t+1) into other buffer ----
#pragma unroll
        for (int nt = 0; nt < 4; nt++) {
            unsigned short o[4];
#pragma unroll
            for (int r = 0; r < 4; r++) {
                float v = fminf(15.f, fmaxf(-15.f, acc[nt][r]));
                float e = __expf(2.0f * v);
                o[r] = f2bf(1.0f - 2.0f / (e + 1.0f));
            }
            int n = n0 + nt * 16 + q * 4;
            us4 v4 = { o[0], o[1], o[2], o[3] };
            *(us4*)&hWr[mcol * 512 + (((n >> 3) ^ mcol) & 63) * 8 + (n & 7)] = v4;
        }
        __syncthreads();   // h(t+1) visible to all waves before next step
    }

    // final h is in buffer (T_SZ & 1) = 0
    unsigned short* hF = sH;

    // ---- fc2 epilogue: waves 0..6 cover 112 >= 100 labels ----
    if (wv < 7) {
        int lA = wv * 16 + mcol; if (lA > 99) lA = 99;
        float4v a2 = {0.f, 0.f, 0.f, 0.f};
#pragma unroll 4
        for (int kt = 0; kt < 16; kt++) {
            short8 fa = *(const short8*)(w_fc2 + lA * 512 + kt * 32 + q * 8);
            short8 bh = *(const short8*)&hF[mcol * 512 + (((kt * 4 + q) ^ mcol) & 63) * 8];
            a2 = mfma16(fa, bh, a2);
        }
#pragma unroll
        for (int r = 0; r < 4; r++) {
            int l = wv * 16 + q * 4 + r;
            if (l < 100) out[(b0 + mcol) * 100 + l] = a2[r] + w_fc2b[l];
        }
    }
}

extern "C" void kernel_launch(void* const* d_in, const int* in_sizes, int n_in,
                              void* d_out, int out_size, void* d_ws, size_t ws_size,
                              hipStream_t stream) {
    unsigned char* base = (unsigned char*)d_ws;
    if (ws_size < (size_t)WS_NEED) {
        void* p = nullptr;
        hipGetSymbolAddress(&p, HIP_SYMBOL(g_blob));
        base = (unsigned char*)p;
    }
    int*            w_x    = (int*)(base + OFF_X);
    unsigned short* w_wh   = (unsigned short*)(base + OFF_WH);
    unsigned short* w_len  = (unsigned short*)(base + OFF_LEN);
    unsigned short* w_ipd  = (unsigned short*)(base + OFF_IPD);
    unsigned short* w_fc2  = (unsigned short*)(base + OFF_FC2);
    unsigned short* w_x2h  = (unsigned short*)(base + OFF_X2H);
    float*          w_fc2b = (float*)(base + OFF_FC2B);
    unsigned short* w_xin  = (unsigned short*)(base + OFF_XIN);

    static bool attr_set = false;
    if (!attr_set) {
        hipFuncSetAttribute((const void*)xin_kernel,
                            hipFuncAttributeMaxDynamicSharedMemorySize, 3 * 128 * 136 * 2);
        hipFuncSetAttribute((const void*)rnn_kernel,
                            hipFuncAttributeMaxDynamicSharedMemorySize, 163840);
        attr_set = true;
    }

    conv_x_kernel<<<256, 256, 0, stream>>>((const int*)d_in[0], w_x);
    conv_floats_kernel<<<1024, 256, 0, stream>>>(
        (const float*)d_in[1], (const float*)d_in[2], (const float*)d_in[7],
        (const float*)d_in[9], (const float*)d_in[5], (const float*)d_in[10],
        w_len, w_ipd, w_wh, w_fc2, w_x2h, w_fc2b);
    xin_kernel<<<1024, 256, 3 * 128 * 136 * 2, stream>>>(
        w_x, w_len, w_ipd,
        (const float*)d_in[3], (const float*)d_in[4],
        w_x2h, (const float*)d_in[6], (const float*)d_in[8],
        w_xin);
    rnn_kernel<<<64, 512, 163840, stream>>>(
        w_wh, w_xin, w_fc2, w_fc2b, (float*)d_out);
}